// Round 9
// baseline (690.773 us; speedup 1.0000x reference)
//
#include <hip/hip_runtime.h>
#include <hip/hip_bf16.h>
#include <hip/hip_cooperative_groups.h>

namespace cg = cooperative_groups;

#define N_NODES 50000
#define N_EDGES 800000
#define BLK     256
#define NTILES  782            // ceil(50000/64)
#define NB_SCAN 196            // fallback path: ceil(50000/256)
#define SMEM_SZ 34816          // 32 KB Bt (xp aliases) + 2 KB rcol/colacc

typedef __attribute__((ext_vector_type(8))) short short8;
typedef __attribute__((ext_vector_type(16))) float f32x16;

struct Params {
  const float* msg; const float* x; const int* ei; const float* ea;
  const float* Wl; const float* bl; const float* Wr; const float* br;
  const float* We; const float* att; const float* bias;
  const float* Wfc; const float* bfc;
  float4* rec; float* nodeF;
  __hip_bfloat16* me_hi; __hip_bfloat16* me_lo;
  int* cnt; float* colsum; int* offs; int* cursor; int* bsum;
  float* w6;
  float* dout;
};

// ================= MFMA tile body =================
// LDS: Bt[2048] short8 (hi 0-1023, lo 1024-2047) at [0,32768);
//      xp (PASS1 transpose, 64*68 floats) ALIASES Bt;
//      rcol/colacc (512 floats) at [32768, 34816).
// Layout: slot = ku*64 + (col^ku)  (ku = 16B k-chunk 0..15, col 0..63)
//   - staging write: 16-lane group has ku 0..15, col fixed -> banks 8x2-way (free)
//   - mfma read: half-wave has col c0..c0+31, ku fixed -> contiguous 512B (free)
template<int PASS>
__device__ __forceinline__ void mfma_tile(const Params& P, int tile, char* SMEM)
{
  short8* Bt   = (short8*)SMEM;
  float*  xp   = (float*)SMEM;
  float*  rcol = (float*)(SMEM + 32768);
  float*  colacc = (float*)(SMEM + 32768);

  const int tid = threadIdx.x;
  const int l = tid & 63, w = tid >> 6;
  const int rt = w >> 1, ct = w & 1;
  const int lrow = l & 31, lhalf = l >> 5;
  const int m0 = tile * 64;
  const int row = m0 + rt * 32 + lrow;

  // ---- A fragments from nodeF (h computed on the fly, split bf16 hi/lo) ----
  float c0a = 0.f, c0b = 0.f, c0d = 0.f, c1a = 0.f, c1b = 0.f, c1d = 0.f;
  bool live = row < N_NODES;
  if (live) {
    const float* nf = P.nodeF + (size_t)row * 8;
    float4 n0 = *(const float4*)nf;        // D0 A00 A10 D1
    float4 n1 = *(const float4*)(nf + 4);  // A01 A11 - -
    float r0 = 1.0f / (n0.x + 1e-16f), r1 = 1.0f / (n0.w + 1e-16f);
    c0a = n0.y * r0; c0b = n0.z * r0; c0d = n0.x * r0;
    c1a = n1.x * r1; c1b = n1.y * r1; c1d = n0.w * r1;
  }
  short8 a_hi[8], a_lo[8];
  #pragma unroll
  for (int ks = 0; ks < 8; ++ks) {
    int k0 = ks * 16 + lhalf * 8;
    float ca = (ks < 4) ? c0a : c1a;
    float cbv = (ks < 4) ? c0b : c1b;
    float cd = (ks < 4) ? c0d : c1d;
    float wA[8], wB[8], wC[8], wD[8];
    *(float4*)&wA[0] = *(const float4*)(P.Wl + k0);
    *(float4*)&wA[4] = *(const float4*)(P.Wl + k0 + 4);
    *(float4*)&wB[0] = *(const float4*)(P.Wl + 128 + k0);
    *(float4*)&wB[4] = *(const float4*)(P.Wl + 128 + k0 + 4);
    *(float4*)&wC[0] = *(const float4*)(P.bl + k0);
    *(float4*)&wC[4] = *(const float4*)(P.bl + k0 + 4);
    *(float4*)&wD[0] = *(const float4*)(P.bias + k0);
    *(float4*)&wD[4] = *(const float4*)(P.bias + k0 + 4);
    short8 hi8, lo8;
    #pragma unroll
    for (int j = 0; j < 8; ++j) {
      float v = ca * wA[j] + cbv * wB[j] + cd * wC[j] + wD[j];
      v = (live && v > 0.f) ? v : 0.f;
      __hip_bfloat16 hb = __float2bfloat16(v);
      float rem = v - __bfloat162float(hb);
      __hip_bfloat16 lb = __float2bfloat16(rem);
      short hs, ls;
      __builtin_memcpy(&hs, &hb, 2);
      __builtin_memcpy(&ls, &lb, 2);
      hi8[j] = hs; lo8[j] = ls;
    }
    a_hi[ks] = hi8; a_lo[ks] = lo8;
  }

  const int colB = ct * 32 + lrow;

  for (int cb = 0; cb < 8; ++cb) {
    __syncthreads();   // (a) prev iter's Bt/xp reads complete
    // stage B cb-block: coalesced global (1KB/wave-instr), swizzled LDS write
    #pragma unroll
    for (int q = 0; q < 8; ++q) {
      int lin = q * 256 + tid;           // 0..2047; q<4 -> hi, q>=4 -> lo
      int s = lin & 1023;
      int col = s >> 4, ku = s & 15;
      int slot = ku * 64 + (col ^ ku);
      size_t gb = ((size_t)(cb * 64 + col) << 7) + ku * 8;
      if (lin < 1024) Bt[slot] = *(const short8*)(P.me_hi + gb);
      else            Bt[1024 + slot] = *(const short8*)(P.me_lo + gb);
    }
    __syncthreads();   // (b) Bt ready

    f32x16 acc = {0.f};
    #pragma unroll
    for (int ks = 0; ks < 8; ++ks) {
      int ku = ks * 2 + lhalf;
      int slot = ku * 64 + (colB ^ ku);
      short8 bh = Bt[slot];
      short8 blo = Bt[1024 + slot];
      acc = __builtin_amdgcn_mfma_f32_32x32x16_bf16(a_hi[ks], bh, acc, 0, 0, 0);
      acc = __builtin_amdgcn_mfma_f32_32x32x16_bf16(a_lo[ks], bh, acc, 0, 0, 0);
      acc = __builtin_amdgcn_mfma_f32_32x32x16_bf16(a_hi[ks], blo, acc, 0, 0, 0);
    }

    if (PASS == 0) {
      float csum = 0.f;
      #pragma unroll
      for (int i = 0; i < 16; ++i) {
        int grow = m0 + rt * 32 + (i & 3) + 8 * (i >> 2) + 4 * lhalf;
        csum += (grow < N_NODES) ? __expf(acc[i]) : 0.f;
      }
      csum += __shfl_xor(csum, 32);
      if (l < 32)
        atomicAdd(&colacc[cb * 64 + ct * 32 + l], csum);   // LDS atomic
    } else {
      __syncthreads(); // (c) all Bt reads done -> xp (alias) free
      #pragma unroll
      for (int i = 0; i < 16; ++i) {
        int rl = rt * 32 + (i & 3) + 8 * (i >> 2) + 4 * lhalf;
        xp[rl * 68 + ct * 32 + lrow] = __expf(acc[i]);
      }
      __syncthreads(); // (d) xp ready
      #pragma unroll
      for (int q = 0; q < 4; ++q) {
        int fid = q * 256 + tid;
        int rl = fid >> 4, c4 = fid & 15;
        int grow = m0 + rl;
        float4 v = *(float4*)&xp[rl * 68 + c4 * 4];
        float4 s = *(const float4*)&rcol[cb * 64 + c4 * 4];
        v.x *= s.x; v.y *= s.y; v.z *= s.z; v.w *= s.w;
        if (grow < N_NODES) {
          *(float4*)&P.dout[(size_t)grow * 1024 + cb * 64 + c4 * 4] = v;
          *(float4*)&P.dout[(size_t)grow * 1024 + 512 + cb * 64 + c4 * 4] = v;
        }
      }
    }
  }
}

// ================= cooperative mega-kernel =================
__global__ __launch_bounds__(BLK, 4) void k_all(Params P)
{
  cg::grid_group gg = cg::this_grid();
  __shared__ __align__(16) char SMEM[SMEM_SZ];
  const int b = blockIdx.x, t = threadIdx.x;
  const int G = gridDim.x;

  // P0: fc (blocks 0-255, 2 rows each) + zero cnt/colsum (256-453) + w6 (454)
  if (b < 256) {
    float* mrow = (float*)SMEM;
    int r = 2 * b + (t >> 7);
    int col = t & 127;
    mrow[t] = P.msg[r * 128 + col];
    __syncthreads();
    int base = (t >> 7) * 128;
    float acc = P.bfc[col];
    #pragma unroll 8
    for (int k = 0; k < 128; ++k) acc = fmaf(mrow[base + k], P.Wfc[k * 128 + col], acc);
    __hip_bfloat16 hi = __float2bfloat16(acc);
    P.me_hi[r * 128 + col] = hi;
    P.me_lo[r * 128 + col] = __float2bfloat16(acc - __bfloat162float(hi));
  } else if (b < 454) {
    int i = (b - 256) * 256 + t;
    if (i < N_NODES + 512) P.cnt[i] = 0;   // cnt + adjacent colsum
  } else if (b == 454 && t < 128) {
    int k = t;
    float4 a = make_float4(P.bl[k] + P.br[k], P.Wl[k], P.Wl[128 + k], P.Wr[k]);
    float4 c = make_float4(P.Wr[128 + k], P.We[k], P.att[k], 0.f);
    *(float4*)&P.w6[k * 8] = a;
    *(float4*)&P.w6[k * 8 + 4] = c;
  }
  gg.sync();

  // P1: histogram of dst
  for (int e = b * BLK + t; e < N_EDGES; e += G * BLK)
    atomicAdd(&P.cnt[P.ei[N_EDGES + e]], 1);
  gg.sync();

  const int CH = (N_NODES + G - 1) / G;    // 49/66/98 for G=1024/768/512

  // P2: per-chunk local exclusive scan (scan width 128, CH <= 128)
  {
    int* sh = (int*)SMEM;
    int base = b * CH;
    if (t < 128) sh[t] = 0;
    __syncthreads();
    int v = 0;
    if (t < CH && base + t < N_NODES) { v = P.cnt[base + t]; sh[t] = v; }
    __syncthreads();
    #pragma unroll
    for (int off = 1; off < 128; off <<= 1) {
      int u = (t < 128 && t >= off) ? sh[t - off] : 0;
      __syncthreads();
      if (t < 128) sh[t] += u;
      __syncthreads();
    }
    if (t < CH && base + t < N_NODES) P.offs[base + t] = sh[t] - v;
    if (t == 0) P.bsum[b] = sh[127];
  }
  gg.sync();

  // P3: every block scans the G block-sums; add-back + cursor init
  {
    int* eb = (int*)SMEM;                // G exclusive values
    int* s3 = eb + 1024;                 // 256 partials
    const int nb = G >> 8;               // 2/3/4
    int xv[4];
    int ssum = 0;
    for (int j = 0; j < nb; ++j) { xv[j] = P.bsum[nb * t + j]; ssum += xv[j]; }
    s3[t] = ssum;
    __syncthreads();
    #pragma unroll
    for (int off = 1; off < 256; off <<= 1) {
      int u = (t >= off) ? s3[t - off] : 0;
      __syncthreads();
      s3[t] += u;
      __syncthreads();
    }
    int p = t ? s3[t - 1] : 0;
    for (int j = 0; j < nb; ++j) { eb[nb * t + j] = p; p += xv[j]; }
    __syncthreads();
    int pb = eb[b];
    int base = b * CH;
    if (t < CH && base + t < N_NODES) {
      int o = P.offs[base + t] + pb;
      P.offs[base + t] = o;
      P.cursor[base + t] = o;
    }
    if (b == 0 && t == 0) P.offs[N_NODES] = N_EDGES;
  }
  gg.sync();

  // P4: fused score + scatter (packed w6 weights)
  {
    const float4* W4 = (const float4*)P.w6;
    for (int e = b * BLK + t; e < N_EDGES; e += G * BLK) {
      int s = P.ei[e], d = P.ei[N_EDGES + e];
      float x0s = P.x[2*s], x1s = P.x[2*s+1];
      float x0d = P.x[2*d], x1d = P.x[2*d+1];
      float av = P.ea[e];
      float s0 = 0.f, s1 = 0.f;
      #pragma unroll 8
      for (int k = 0; k < 64; ++k) {
        float4 a = W4[2*k], c = W4[2*k+1];
        float m = a.x;
        m = fmaf(x0s, a.y, m);
        m = fmaf(x1s, a.z, m);
        m = fmaf(x0d, a.w, m);
        m = fmaf(x1d, c.x, m);
        m = fmaf(av,  c.y, m);
        s0 = fmaf(fmaxf(m, 0.2f * m), c.z, s0);
      }
      #pragma unroll 8
      for (int k = 64; k < 128; ++k) {
        float4 a = W4[2*k], c = W4[2*k+1];
        float m = a.x;
        m = fmaf(x0s, a.y, m);
        m = fmaf(x1s, a.z, m);
        m = fmaf(x0d, a.w, m);
        m = fmaf(x1d, c.x, m);
        m = fmaf(av,  c.y, m);
        s1 = fmaf(fmaxf(m, 0.2f * m), c.z, s1);
      }
      int pos = atomicAdd(&P.cursor[d], 1);
      P.rec[pos] = make_float4(s0, s1, x0s, x1s);
    }
  }
  gg.sync();

  // P5: per-node gather reduction
  {
    int n = b * BLK + t;
    if (n < N_NODES) {
      int a = P.offs[n], bb = P.offs[n + 1];
      float D0 = 0.f, A00 = 0.f, A10 = 0.f;
      float D1 = 0.f, A01 = 0.f, A11 = 0.f;
      for (int i = a; i < bb; ++i) {
        float4 r = P.rec[i];
        float e0 = __expf(r.x);
        float e1 = __expf(r.y);
        D0 += e0; A00 += e0 * r.z; A10 += e0 * r.w;
        D1 += e1; A01 += e1 * r.z; A11 += e1 * r.w;
      }
      float* nf = P.nodeF + (size_t)n * 8;
      nf[0] = D0; nf[1] = A00; nf[2] = A10;
      nf[3] = D1; nf[4] = A01; nf[5] = A11;
    }
  }
  gg.sync();

  // P6: MFMA colsum pass
  {
    float* colacc = (float*)(SMEM + 32768);
    colacc[t] = 0.f; colacc[t + 256] = 0.f;
    __syncthreads();
    for (int tile = b; tile < NTILES; tile += G)
      mfma_tile<0>(P, tile, SMEM);
    __syncthreads();
    atomicAdd(&P.colsum[t], colacc[t]);
    atomicAdd(&P.colsum[t + 256], colacc[t + 256]);
  }
  gg.sync();

  // P7: MFMA normalize + store pass
  {
    float* rcol = (float*)(SMEM + 32768);
    rcol[t] = 1.0f / P.colsum[t];
    rcol[t + 256] = 1.0f / P.colsum[t + 256];
    __syncthreads();
    for (int tile = b; tile < NTILES; tile += G)
      mfma_tile<1>(P, tile, SMEM);
  }
}

// ================= fallback multi-kernel path =================
__global__ __launch_bounds__(256) void k_zero(int* __restrict__ buf)
{
  int i = blockIdx.x * 256 + threadIdx.x;
  if (i < N_NODES + 512) buf[i] = 0;
}

__global__ __launch_bounds__(256) void k_hist(
    const int* __restrict__ ei, int* __restrict__ cnt)
{
  int e = blockIdx.x * 256 + threadIdx.x;
  if (e >= N_EDGES) return;
  atomicAdd(&cnt[ei[N_EDGES + e]], 1);
}

__global__ __launch_bounds__(256) void k_scan1(
    const int* __restrict__ cnt, int* __restrict__ offs, int* __restrict__ bsum)
{
  __shared__ int sh[256];
  int b = blockIdx.x, t = threadIdx.x;
  int i = b * 256 + t;
  int v = (i < N_NODES) ? cnt[i] : 0;
  sh[t] = v;
  __syncthreads();
  #pragma unroll
  for (int off = 1; off < 256; off <<= 1) {
    int u = (t >= off) ? sh[t - off] : 0;
    __syncthreads();
    sh[t] += u;
    __syncthreads();
  }
  if (i < N_NODES) offs[i] = sh[t] - v;
  if (t == 255) bsum[b] = sh[255];
}

__global__ __launch_bounds__(256) void k_scan2(int* __restrict__ bsum)
{
  __shared__ int sh[256];
  int t = threadIdx.x;
  int v = (t < NB_SCAN) ? bsum[t] : 0;
  sh[t] = v;
  __syncthreads();
  #pragma unroll
  for (int off = 1; off < 256; off <<= 1) {
    int u = (t >= off) ? sh[t - off] : 0;
    __syncthreads();
    sh[t] += u;
    __syncthreads();
  }
  if (t < NB_SCAN) bsum[t] = sh[t] - v;
}

__global__ __launch_bounds__(256) void k_scan3(
    int* __restrict__ offs, const int* __restrict__ bsum, int* __restrict__ cursor)
{
  int b = blockIdx.x, t = threadIdx.x;
  int i = b * 256 + t;
  if (i < N_NODES) {
    int o = offs[i] + bsum[b];
    offs[i] = o;
    cursor[i] = o;
  }
  if (b == 0 && t == 0) offs[N_NODES] = N_EDGES;
}

__global__ void k_w6(Params P)
{
  int k = threadIdx.x;
  if (k < 128) {
    float4 a = make_float4(P.bl[k] + P.br[k], P.Wl[k], P.Wl[128 + k], P.Wr[k]);
    float4 c = make_float4(P.Wr[128 + k], P.We[k], P.att[k], 0.f);
    *(float4*)&P.w6[k * 8] = a;
    *(float4*)&P.w6[k * 8 + 4] = c;
  }
}

__global__ __launch_bounds__(256) void k_scatter(Params P)
{
  int e = blockIdx.x * 256 + threadIdx.x;
  if (e >= N_EDGES) return;
  const float4* W4 = (const float4*)P.w6;
  int s = P.ei[e], d = P.ei[N_EDGES + e];
  float x0s = P.x[2*s], x1s = P.x[2*s+1];
  float x0d = P.x[2*d], x1d = P.x[2*d+1];
  float av = P.ea[e];
  float s0 = 0.f, s1 = 0.f;
  #pragma unroll 8
  for (int k = 0; k < 64; ++k) {
    float4 a = W4[2*k], c = W4[2*k+1];
    float m = a.x;
    m = fmaf(x0s, a.y, m);
    m = fmaf(x1s, a.z, m);
    m = fmaf(x0d, a.w, m);
    m = fmaf(x1d, c.x, m);
    m = fmaf(av,  c.y, m);
    s0 = fmaf(fmaxf(m, 0.2f * m), c.z, s0);
  }
  #pragma unroll 8
  for (int k = 64; k < 128; ++k) {
    float4 a = W4[2*k], c = W4[2*k+1];
    float m = a.x;
    m = fmaf(x0s, a.y, m);
    m = fmaf(x1s, a.z, m);
    m = fmaf(x0d, a.w, m);
    m = fmaf(x1d, c.x, m);
    m = fmaf(av,  c.y, m);
    s1 = fmaf(fmaxf(m, 0.2f * m), c.z, s1);
  }
  int pos = atomicAdd(&P.cursor[d], 1);
  P.rec[pos] = make_float4(s0, s1, x0s, x1s);
}

__global__ __launch_bounds__(256) void k_gather(Params P)
{
  int n = blockIdx.x * 256 + threadIdx.x;
  if (n >= N_NODES) return;
  int a = P.offs[n], b = P.offs[n + 1];
  float D0 = 0.f, A00 = 0.f, A10 = 0.f;
  float D1 = 0.f, A01 = 0.f, A11 = 0.f;
  for (int i = a; i < b; ++i) {
    float4 r = P.rec[i];
    float e0 = __expf(r.x);
    float e1 = __expf(r.y);
    D0 += e0; A00 += e0 * r.z; A10 += e0 * r.w;
    D1 += e1; A01 += e1 * r.z; A11 += e1 * r.w;
  }
  float* nf = P.nodeF + (size_t)n * 8;
  nf[0] = D0; nf[1] = A00; nf[2] = A10;
  nf[3] = D1; nf[4] = A01; nf[5] = A11;
}

__global__ __launch_bounds__(128) void k_fc(Params P)
{
  int j = blockIdx.x, k = threadIdx.x;
  __shared__ float mrow[128];
  mrow[k] = P.msg[j*128 + k];
  __syncthreads();
  float acc = P.bfc[k];
  #pragma unroll 8
  for (int t = 0; t < 128; ++t) acc = fmaf(mrow[t], P.Wfc[t*128 + k], acc);
  __hip_bfloat16 hi = __float2bfloat16(acc);
  P.me_hi[j*128 + k] = hi;
  P.me_lo[j*128 + k] = __float2bfloat16(acc - __bfloat162float(hi));
}

template<int PASS>
__global__ __launch_bounds__(256, 4) void k_mfma(Params P)
{
  __shared__ __align__(16) char SMEM[SMEM_SZ];
  int tid = threadIdx.x;
  if (PASS == 0) {
    float* colacc = (float*)(SMEM + 32768);
    colacc[tid] = 0.f; colacc[tid + 256] = 0.f;
    __syncthreads();
    mfma_tile<0>(P, blockIdx.x, SMEM);
    __syncthreads();
    atomicAdd(&P.colsum[tid], colacc[tid]);
    atomicAdd(&P.colsum[tid + 256], colacc[tid + 256]);
  } else {
    float* rcol = (float*)(SMEM + 32768);
    rcol[tid] = 1.0f / P.colsum[tid];
    rcol[tid + 256] = 1.0f / P.colsum[tid + 256];
    __syncthreads();
    mfma_tile<1>(P, blockIdx.x, SMEM);
  }
}

extern "C" void kernel_launch(void* const* d_in, const int* in_sizes, int n_in,
                              void* d_out, int out_size, void* d_ws, size_t ws_size,
                              hipStream_t stream)
{
  Params P;
  P.msg = (const float*)d_in[0];
  P.x   = (const float*)d_in[1];
  P.ei  = (const int*)d_in[2];
  P.ea  = (const float*)d_in[3];
  // conv1 params (d_in[4..10]) are dead code in the reference
  P.Wl   = (const float*)d_in[11];
  P.bl   = (const float*)d_in[12];
  P.Wr   = (const float*)d_in[13];
  P.br   = (const float*)d_in[14];
  P.We   = (const float*)d_in[15];
  P.att  = (const float*)d_in[16];
  P.bias = (const float*)d_in[17];
  P.Wfc  = (const float*)d_in[18];
  P.bfc  = (const float*)d_in[19];

  char* p = (char*)d_ws;
  P.rec = (float4*)p;                    p += (size_t)N_EDGES * 16;
  P.nodeF = (float*)p;                   p += (size_t)N_NODES * 8 * 4;
  P.me_hi = (__hip_bfloat16*)p;          p += 512 * 128 * 2;
  P.me_lo = (__hip_bfloat16*)p;          p += 512 * 128 * 2;
  P.cnt = (int*)p;                       p += (size_t)N_NODES * 4;   // colsum adjacent
  P.colsum = (float*)p;                  p += 512 * 4;
  P.offs = (int*)p;                      p += (size_t)(N_NODES + 1) * 4;
  P.cursor = (int*)p;                    p += (size_t)N_NODES * 4;
  P.bsum = (int*)p;                      p += 1024 * 4;
  P.w6 = (float*)p;                      p += 128 * 8 * 4;
  P.dout = (float*)d_out;

  // occupancy-cascaded cooperative launch, multi-kernel fallback
  int maxBlk = 0;
  hipError_t qerr = hipOccupancyMaxActiveBlocksPerMultiprocessor(&maxBlk, k_all, BLK, 0);
  if (qerr == hipSuccess && maxBlk >= 2) {
    int g = (maxBlk >= 4) ? 1024 : (maxBlk >= 3 ? 768 : 512);
    void* args[] = { &P };
    hipError_t lerr = hipLaunchCooperativeKernel((void*)k_all, dim3(g), dim3(BLK),
                                                 args, 0, stream);
    if (lerr == hipSuccess) return;
  }

  // ---- fallback: proven multi-kernel pipeline ----
  k_zero<<<(N_NODES + 512 + 255) / 256, 256, 0, stream>>>(P.cnt);
  k_hist<<<(N_EDGES + 255) / 256, 256, 0, stream>>>(P.ei, P.cnt);
  k_scan1<<<NB_SCAN, 256, 0, stream>>>(P.cnt, P.offs, P.bsum);
  k_scan2<<<1, 256, 0, stream>>>(P.bsum);
  k_scan3<<<NB_SCAN, 256, 0, stream>>>(P.offs, P.bsum, P.cursor);
  k_w6<<<1, 128, 0, stream>>>(P);
  k_scatter<<<(N_EDGES + 255) / 256, 256, 0, stream>>>(P);
  k_gather<<<(N_NODES + 255) / 256, 256, 0, stream>>>(P);
  k_fc<<<512, 128, 0, stream>>>(P);
  k_mfma<0><<<NTILES, 256, 0, stream>>>(P);
  k_mfma<1><<<NTILES, 256, 0, stream>>>(P);
}

// Round 10
// 234.446 us; speedup vs baseline: 2.9464x; 2.9464x over previous
//
#include <hip/hip_runtime.h>
#include <hip/hip_bf16.h>
#include <hip/hip_cooperative_groups.h>

namespace cg = cooperative_groups;

#define N_NODES 50000
#define N_EDGES 800000
#define BLK     256
#define NTILES  782            // ceil(50000/64)
#define NB_SCAN 196            // fallback path: ceil(50000/256)
#define SMEM_SZ 34816          // 32 KB Bt (xp aliases) + 2 KB rcol/colacc

typedef __attribute__((ext_vector_type(8))) short short8;
typedef __attribute__((ext_vector_type(16))) float f32x16;

struct Params {
  const float* msg; const float* x; const int* ei; const float* ea;
  const float* Wl; const float* bl; const float* Wr; const float* br;
  const float* We; const float* att; const float* bias;
  const float* Wfc; const float* bfc;
  float4* rec; float* nodeF;
  __hip_bfloat16* me_hi; __hip_bfloat16* me_lo;
  int* cnt; float* colsum; int* offs; int* cursor; int* bsum;
  float* w6;
  float* dout;
};

// ================= MFMA tile body =================
// LDS: Bt[2048] short8 (hi 0-1023, lo 1024-2047) at [0,32768);
//      xp (PASS1 transpose, 64*68 floats) ALIASES Bt;
//      rcol/colacc (512 floats) at [32768, 34816).
// Layout: slot = ku*64 + (col^ku)  (ku = 16B k-chunk 0..15, col 0..63)
//   - staging write: 16-lane group has ku 0..15, col fixed -> 8 banks x 2-way (free)
//   - mfma read: half-wave has col c0..c0+31, ku fixed -> contiguous 512B (free)
template<int PASS>
__device__ __forceinline__ void mfma_tile(const Params& P, int tile, char* SMEM)
{
  short8* Bt   = (short8*)SMEM;
  float*  xp   = (float*)SMEM;
  float*  rcol = (float*)(SMEM + 32768);
  float*  colacc = (float*)(SMEM + 32768);

  const int tid = threadIdx.x;
  const int l = tid & 63, w = tid >> 6;
  const int rt = w >> 1, ct = w & 1;
  const int lrow = l & 31, lhalf = l >> 5;
  const int m0 = tile * 64;
  const int row = m0 + rt * 32 + lrow;

  // ---- A fragments from nodeF (h computed on the fly, split bf16 hi/lo) ----
  float c0a = 0.f, c0b = 0.f, c0d = 0.f, c1a = 0.f, c1b = 0.f, c1d = 0.f;
  bool live = row < N_NODES;
  if (live) {
    const float* nf = P.nodeF + (size_t)row * 8;
    float4 n0 = *(const float4*)nf;        // D0 A00 A10 D1
    float4 n1 = *(const float4*)(nf + 4);  // A01 A11 - -
    float r0 = 1.0f / (n0.x + 1e-16f), r1 = 1.0f / (n0.w + 1e-16f);
    c0a = n0.y * r0; c0b = n0.z * r0; c0d = n0.x * r0;
    c1a = n1.x * r1; c1b = n1.y * r1; c1d = n0.w * r1;
  }
  short8 a_hi[8], a_lo[8];
  #pragma unroll
  for (int ks = 0; ks < 8; ++ks) {
    int k0 = ks * 16 + lhalf * 8;
    float ca = (ks < 4) ? c0a : c1a;
    float cbv = (ks < 4) ? c0b : c1b;
    float cd = (ks < 4) ? c0d : c1d;
    float wA[8], wB[8], wC[8], wD[8];
    *(float4*)&wA[0] = *(const float4*)(P.Wl + k0);
    *(float4*)&wA[4] = *(const float4*)(P.Wl + k0 + 4);
    *(float4*)&wB[0] = *(const float4*)(P.Wl + 128 + k0);
    *(float4*)&wB[4] = *(const float4*)(P.Wl + 128 + k0 + 4);
    *(float4*)&wC[0] = *(const float4*)(P.bl + k0);
    *(float4*)&wC[4] = *(const float4*)(P.bl + k0 + 4);
    *(float4*)&wD[0] = *(const float4*)(P.bias + k0);
    *(float4*)&wD[4] = *(const float4*)(P.bias + k0 + 4);
    short8 hi8, lo8;
    #pragma unroll
    for (int j = 0; j < 8; ++j) {
      float v = ca * wA[j] + cbv * wB[j] + cd * wC[j] + wD[j];
      v = (live && v > 0.f) ? v : 0.f;
      __hip_bfloat16 hb = __float2bfloat16(v);
      float rem = v - __bfloat162float(hb);
      __hip_bfloat16 lb = __float2bfloat16(rem);
      short hs, ls;
      __builtin_memcpy(&hs, &hb, 2);
      __builtin_memcpy(&ls, &lb, 2);
      hi8[j] = hs; lo8[j] = ls;
    }
    a_hi[ks] = hi8; a_lo[ks] = lo8;
  }

  const int colB = ct * 32 + lrow;

  for (int cb = 0; cb < 8; ++cb) {
    __syncthreads();   // (a) prev iter's Bt/xp reads complete
    // stage B cb-block: coalesced global (1KB/wave-instr), swizzled LDS write
    #pragma unroll
    for (int q = 0; q < 8; ++q) {
      int lin = q * 256 + tid;           // 0..2047; q<4 -> hi, q>=4 -> lo
      int s = lin & 1023;
      int col = s >> 4, ku = s & 15;
      int slot = ku * 64 + (col ^ ku);
      size_t gb = ((size_t)(cb * 64 + col) << 7) + ku * 8;
      if (lin < 1024) Bt[slot] = *(const short8*)(P.me_hi + gb);
      else            Bt[1024 + slot] = *(const short8*)(P.me_lo + gb);
    }
    __syncthreads();   // (b) Bt ready

    f32x16 acc = {0.f};
    #pragma unroll
    for (int ks = 0; ks < 8; ++ks) {
      int ku = ks * 2 + lhalf;
      int slot = ku * 64 + (colB ^ ku);
      short8 bh = Bt[slot];
      short8 blo = Bt[1024 + slot];
      acc = __builtin_amdgcn_mfma_f32_32x32x16_bf16(a_hi[ks], bh, acc, 0, 0, 0);
      acc = __builtin_amdgcn_mfma_f32_32x32x16_bf16(a_lo[ks], bh, acc, 0, 0, 0);
      acc = __builtin_amdgcn_mfma_f32_32x32x16_bf16(a_hi[ks], blo, acc, 0, 0, 0);
    }

    if (PASS == 0) {
      float csum = 0.f;
      #pragma unroll
      for (int i = 0; i < 16; ++i) {
        int grow = m0 + rt * 32 + (i & 3) + 8 * (i >> 2) + 4 * lhalf;
        csum += (grow < N_NODES) ? __expf(acc[i]) : 0.f;
      }
      csum += __shfl_xor(csum, 32);
      if (l < 32)
        atomicAdd(&colacc[cb * 64 + ct * 32 + l], csum);   // LDS atomic
    } else {
      __syncthreads(); // (c) all Bt reads done -> xp (alias) free
      #pragma unroll
      for (int i = 0; i < 16; ++i) {
        int rl = rt * 32 + (i & 3) + 8 * (i >> 2) + 4 * lhalf;
        xp[rl * 68 + ct * 32 + lrow] = __expf(acc[i]);
      }
      __syncthreads(); // (d) xp ready
      #pragma unroll
      for (int q = 0; q < 4; ++q) {
        int fid = q * 256 + tid;
        int rl = fid >> 4, c4 = fid & 15;
        int grow = m0 + rl;
        float4 v = *(float4*)&xp[rl * 68 + c4 * 4];
        float4 s = *(const float4*)&rcol[cb * 64 + c4 * 4];
        v.x *= s.x; v.y *= s.y; v.z *= s.z; v.w *= s.w;
        if (grow < N_NODES) {
          *(float4*)&P.dout[(size_t)grow * 1024 + cb * 64 + c4 * 4] = v;
          *(float4*)&P.dout[(size_t)grow * 1024 + 512 + cb * 64 + c4 * 4] = v;
        }
      }
    }
  }
}

// ================= cooperative mega-kernel =================
__global__ __launch_bounds__(BLK, 3) void k_all(Params P)
{
  cg::grid_group gg = cg::this_grid();
  __shared__ __align__(16) char SMEM[SMEM_SZ];
  const int b = blockIdx.x, t = threadIdx.x;
  const int G = gridDim.x;

  // P0: fc (blocks 0-255, 2 rows each) + zero cnt/colsum (256-453) + w6 (454)
  if (b < 256) {
    float* mrow = (float*)SMEM;
    int r = 2 * b + (t >> 7);
    int col = t & 127;
    mrow[t] = P.msg[r * 128 + col];
    __syncthreads();
    int base = (t >> 7) * 128;
    float acc = P.bfc[col];
    #pragma unroll 8
    for (int k = 0; k < 128; ++k) acc = fmaf(mrow[base + k], P.Wfc[k * 128 + col], acc);
    __hip_bfloat16 hi = __float2bfloat16(acc);
    P.me_hi[r * 128 + col] = hi;
    P.me_lo[r * 128 + col] = __float2bfloat16(acc - __bfloat162float(hi));
  } else if (b < 454) {
    int i = (b - 256) * 256 + t;
    if (i < N_NODES + 512) P.cnt[i] = 0;   // cnt + adjacent colsum
  } else if (b == 454 && t < 128) {
    int k = t;
    float4 a = make_float4(P.bl[k] + P.br[k], P.Wl[k], P.Wl[128 + k], P.Wr[k]);
    float4 c = make_float4(P.Wr[128 + k], P.We[k], P.att[k], 0.f);
    *(float4*)&P.w6[k * 8] = a;
    *(float4*)&P.w6[k * 8 + 4] = c;
  }
  gg.sync();

  // P1: histogram of dst
  for (int e = b * BLK + t; e < N_EDGES; e += G * BLK)
    atomicAdd(&P.cnt[P.ei[N_EDGES + e]], 1);
  gg.sync();

  const int CH = (N_NODES + G - 1) / G;    // 66/98 for G=768/512

  // P2: per-chunk local exclusive scan (scan width 128, CH <= 128)
  {
    int* sh = (int*)SMEM;
    int base = b * CH;
    if (t < 128) sh[t] = 0;
    __syncthreads();
    int v = 0;
    if (t < 128 && t < CH && base + t < N_NODES) { v = P.cnt[base + t]; sh[t] = v; }
    __syncthreads();
    #pragma unroll
    for (int off = 1; off < 128; off <<= 1) {
      int u = (t < 128 && t >= off) ? sh[t - off] : 0;
      __syncthreads();
      if (t < 128) sh[t] += u;
      __syncthreads();
    }
    if (t < 128 && t < CH && base + t < N_NODES) P.offs[base + t] = sh[t] - v;
    if (t == 0) P.bsum[b] = sh[127];
  }
  gg.sync();

  // P3: every block scans the G block-sums; add-back + cursor init
  {
    int* eb = (int*)SMEM;                // G exclusive values
    int* s3 = eb + 1024;                 // 256 partials
    const int nb = G >> 8;               // 2/3
    int xv[4];
    int ssum = 0;
    for (int j = 0; j < nb; ++j) { xv[j] = P.bsum[nb * t + j]; ssum += xv[j]; }
    s3[t] = ssum;
    __syncthreads();
    #pragma unroll
    for (int off = 1; off < 256; off <<= 1) {
      int u = (t >= off) ? s3[t - off] : 0;
      __syncthreads();
      s3[t] += u;
      __syncthreads();
    }
    int p = t ? s3[t - 1] : 0;
    for (int j = 0; j < nb; ++j) { eb[nb * t + j] = p; p += xv[j]; }
    __syncthreads();
    int pb = eb[b];
    int base = b * CH;
    if (t < CH && base + t < N_NODES) {
      int o = P.offs[base + t] + pb;
      P.offs[base + t] = o;
      P.cursor[base + t] = o;
    }
    if (b == 0 && t == 0) P.offs[N_NODES] = N_EDGES;
  }
  gg.sync();

  // P4: fused score + scatter (packed w6 weights)
  {
    const float4* W4 = (const float4*)P.w6;
    for (int e = b * BLK + t; e < N_EDGES; e += G * BLK) {
      int s = P.ei[e], d = P.ei[N_EDGES + e];
      float x0s = P.x[2*s], x1s = P.x[2*s+1];
      float x0d = P.x[2*d], x1d = P.x[2*d+1];
      float av = P.ea[e];
      float s0 = 0.f, s1 = 0.f;
      #pragma unroll 8
      for (int k = 0; k < 64; ++k) {
        float4 a = W4[2*k], c = W4[2*k+1];
        float m = a.x;
        m = fmaf(x0s, a.y, m);
        m = fmaf(x1s, a.z, m);
        m = fmaf(x0d, a.w, m);
        m = fmaf(x1d, c.x, m);
        m = fmaf(av,  c.y, m);
        s0 = fmaf(fmaxf(m, 0.2f * m), c.z, s0);
      }
      #pragma unroll 8
      for (int k = 64; k < 128; ++k) {
        float4 a = W4[2*k], c = W4[2*k+1];
        float m = a.x;
        m = fmaf(x0s, a.y, m);
        m = fmaf(x1s, a.z, m);
        m = fmaf(x0d, a.w, m);
        m = fmaf(x1d, c.x, m);
        m = fmaf(av,  c.y, m);
        s1 = fmaf(fmaxf(m, 0.2f * m), c.z, s1);
      }
      int pos = atomicAdd(&P.cursor[d], 1);
      P.rec[pos] = make_float4(s0, s1, x0s, x1s);
    }
  }
  gg.sync();

  // P5: per-node gather reduction
  {
    int n = b * BLK + t;
    if (n < N_NODES) {
      int a = P.offs[n], bb = P.offs[n + 1];
      float D0 = 0.f, A00 = 0.f, A10 = 0.f;
      float D1 = 0.f, A01 = 0.f, A11 = 0.f;
      for (int i = a; i < bb; ++i) {
        float4 r = P.rec[i];
        float e0 = __expf(r.x);
        float e1 = __expf(r.y);
        D0 += e0; A00 += e0 * r.z; A10 += e0 * r.w;
        D1 += e1; A01 += e1 * r.z; A11 += e1 * r.w;
      }
      float* nf = P.nodeF + (size_t)n * 8;
      nf[0] = D0; nf[1] = A00; nf[2] = A10;
      nf[3] = D1; nf[4] = A01; nf[5] = A11;
    }
  }
  gg.sync();

  // P6: MFMA colsum pass
  {
    float* colacc = (float*)(SMEM + 32768);
    colacc[t] = 0.f; colacc[t + 256] = 0.f;
    __syncthreads();
    for (int tile = b; tile < NTILES; tile += G)
      mfma_tile<0>(P, tile, SMEM);
    __syncthreads();
    atomicAdd(&P.colsum[t], colacc[t]);
    atomicAdd(&P.colsum[t + 256], colacc[t + 256]);
  }
  gg.sync();

  // P7: MFMA normalize + store pass
  {
    float* rcol = (float*)(SMEM + 32768);
    rcol[t] = 1.0f / P.colsum[t];
    rcol[t + 256] = 1.0f / P.colsum[t + 256];
    __syncthreads();
    for (int tile = b; tile < NTILES; tile += G)
      mfma_tile<1>(P, tile, SMEM);
  }
}

// ================= fallback multi-kernel path =================
__global__ __launch_bounds__(256) void k_zero(int* __restrict__ buf)
{
  int i = blockIdx.x * 256 + threadIdx.x;
  if (i < N_NODES + 512) buf[i] = 0;
}

__global__ __launch_bounds__(256) void k_hist(
    const int* __restrict__ ei, int* __restrict__ cnt)
{
  int e = blockIdx.x * 256 + threadIdx.x;
  if (e >= N_EDGES) return;
  atomicAdd(&cnt[ei[N_EDGES + e]], 1);
}

__global__ __launch_bounds__(256) void k_scan1(
    const int* __restrict__ cnt, int* __restrict__ offs, int* __restrict__ bsum)
{
  __shared__ int sh[256];
  int b = blockIdx.x, t = threadIdx.x;
  int i = b * 256 + t;
  int v = (i < N_NODES) ? cnt[i] : 0;
  sh[t] = v;
  __syncthreads();
  #pragma unroll
  for (int off = 1; off < 256; off <<= 1) {
    int u = (t >= off) ? sh[t - off] : 0;
    __syncthreads();
    sh[t] += u;
    __syncthreads();
  }
  if (i < N_NODES) offs[i] = sh[t] - v;
  if (t == 255) bsum[b] = sh[255];
}

__global__ __launch_bounds__(256) void k_scan2(int* __restrict__ bsum)
{
  __shared__ int sh[256];
  int t = threadIdx.x;
  int v = (t < NB_SCAN) ? bsum[t] : 0;
  sh[t] = v;
  __syncthreads();
  #pragma unroll
  for (int off = 1; off < 256; off <<= 1) {
    int u = (t >= off) ? sh[t - off] : 0;
    __syncthreads();
    sh[t] += u;
    __syncthreads();
  }
  if (t < NB_SCAN) bsum[t] = sh[t] - v;
}

__global__ __launch_bounds__(256) void k_scan3(
    int* __restrict__ offs, const int* __restrict__ bsum, int* __restrict__ cursor)
{
  int b = blockIdx.x, t = threadIdx.x;
  int i = b * 256 + t;
  if (i < N_NODES) {
    int o = offs[i] + bsum[b];
    offs[i] = o;
    cursor[i] = o;
  }
  if (b == 0 && t == 0) offs[N_NODES] = N_EDGES;
}

__global__ void k_w6(Params P)
{
  int k = threadIdx.x;
  if (k < 128) {
    float4 a = make_float4(P.bl[k] + P.br[k], P.Wl[k], P.Wl[128 + k], P.Wr[k]);
    float4 c = make_float4(P.Wr[128 + k], P.We[k], P.att[k], 0.f);
    *(float4*)&P.w6[k * 8] = a;
    *(float4*)&P.w6[k * 8 + 4] = c;
  }
}

__global__ __launch_bounds__(256) void k_scatter(Params P)
{
  int e = blockIdx.x * 256 + threadIdx.x;
  if (e >= N_EDGES) return;
  const float4* W4 = (const float4*)P.w6;
  int s = P.ei[e], d = P.ei[N_EDGES + e];
  float x0s = P.x[2*s], x1s = P.x[2*s+1];
  float x0d = P.x[2*d], x1d = P.x[2*d+1];
  float av = P.ea[e];
  float s0 = 0.f, s1 = 0.f;
  #pragma unroll 8
  for (int k = 0; k < 64; ++k) {
    float4 a = W4[2*k], c = W4[2*k+1];
    float m = a.x;
    m = fmaf(x0s, a.y, m);
    m = fmaf(x1s, a.z, m);
    m = fmaf(x0d, a.w, m);
    m = fmaf(x1d, c.x, m);
    m = fmaf(av,  c.y, m);
    s0 = fmaf(fmaxf(m, 0.2f * m), c.z, s0);
  }
  #pragma unroll 8
  for (int k = 64; k < 128; ++k) {
    float4 a = W4[2*k], c = W4[2*k+1];
    float m = a.x;
    m = fmaf(x0s, a.y, m);
    m = fmaf(x1s, a.z, m);
    m = fmaf(x0d, a.w, m);
    m = fmaf(x1d, c.x, m);
    m = fmaf(av,  c.y, m);
    s1 = fmaf(fmaxf(m, 0.2f * m), c.z, s1);
  }
  int pos = atomicAdd(&P.cursor[d], 1);
  P.rec[pos] = make_float4(s0, s1, x0s, x1s);
}

__global__ __launch_bounds__(256) void k_gather(Params P)
{
  int n = blockIdx.x * 256 + threadIdx.x;
  if (n >= N_NODES) return;
  int a = P.offs[n], b = P.offs[n + 1];
  float D0 = 0.f, A00 = 0.f, A10 = 0.f;
  float D1 = 0.f, A01 = 0.f, A11 = 0.f;
  for (int i = a; i < b; ++i) {
    float4 r = P.rec[i];
    float e0 = __expf(r.x);
    float e1 = __expf(r.y);
    D0 += e0; A00 += e0 * r.z; A10 += e0 * r.w;
    D1 += e1; A01 += e1 * r.z; A11 += e1 * r.w;
  }
  float* nf = P.nodeF + (size_t)n * 8;
  nf[0] = D0; nf[1] = A00; nf[2] = A10;
  nf[3] = D1; nf[4] = A01; nf[5] = A11;
}

__global__ __launch_bounds__(128) void k_fc(Params P)
{
  int j = blockIdx.x, k = threadIdx.x;
  __shared__ float mrow[128];
  mrow[k] = P.msg[j*128 + k];
  __syncthreads();
  float acc = P.bfc[k];
  #pragma unroll 8
  for (int t = 0; t < 128; ++t) acc = fmaf(mrow[t], P.Wfc[t*128 + k], acc);
  __hip_bfloat16 hi = __float2bfloat16(acc);
  P.me_hi[j*128 + k] = hi;
  P.me_lo[j*128 + k] = __float2bfloat16(acc - __bfloat162float(hi));
}

template<int PASS>
__global__ __launch_bounds__(256, 3) void k_mfma(Params P)
{
  __shared__ __align__(16) char SMEM[SMEM_SZ];
  int tid = threadIdx.x;
  if (PASS == 0) {
    float* colacc = (float*)(SMEM + 32768);
    colacc[tid] = 0.f; colacc[tid + 256] = 0.f;
    __syncthreads();
    mfma_tile<0>(P, blockIdx.x, SMEM);
    __syncthreads();
    atomicAdd(&P.colsum[tid], colacc[tid]);
    atomicAdd(&P.colsum[tid + 256], colacc[tid + 256]);
  } else {
    float* rcol = (float*)(SMEM + 32768);
    rcol[tid] = 1.0f / P.colsum[tid];
    rcol[tid + 256] = 1.0f / P.colsum[tid + 256];
    __syncthreads();
    mfma_tile<1>(P, blockIdx.x, SMEM);
  }
}

extern "C" void kernel_launch(void* const* d_in, const int* in_sizes, int n_in,
                              void* d_out, int out_size, void* d_ws, size_t ws_size,
                              hipStream_t stream)
{
  Params P;
  P.msg = (const float*)d_in[0];
  P.x   = (const float*)d_in[1];
  P.ei  = (const int*)d_in[2];
  P.ea  = (const float*)d_in[3];
  // conv1 params (d_in[4..10]) are dead code in the reference
  P.Wl   = (const float*)d_in[11];
  P.bl   = (const float*)d_in[12];
  P.Wr   = (const float*)d_in[13];
  P.br   = (const float*)d_in[14];
  P.We   = (const float*)d_in[15];
  P.att  = (const float*)d_in[16];
  P.bias = (const float*)d_in[17];
  P.Wfc  = (const float*)d_in[18];
  P.bfc  = (const float*)d_in[19];

  char* p = (char*)d_ws;
  P.rec = (float4*)p;                    p += (size_t)N_EDGES * 16;
  P.nodeF = (float*)p;                   p += (size_t)N_NODES * 8 * 4;
  P.me_hi = (__hip_bfloat16*)p;          p += 512 * 128 * 2;
  P.me_lo = (__hip_bfloat16*)p;          p += 512 * 128 * 2;
  P.cnt = (int*)p;                       p += (size_t)N_NODES * 4;   // colsum adjacent
  P.colsum = (float*)p;                  p += 512 * 4;
  P.offs = (int*)p;                      p += (size_t)(N_NODES + 1) * 4;
  P.cursor = (int*)p;                    p += (size_t)N_NODES * 4;
  P.bsum = (int*)p;                      p += 1024 * 4;
  P.w6 = (float*)p;                      p += 128 * 8 * 4;
  P.dout = (float*)d_out;

  // occupancy-cascaded cooperative launch, multi-kernel fallback
  int maxBlk = 0;
  hipError_t qerr = hipOccupancyMaxActiveBlocksPerMultiprocessor(&maxBlk, k_all, BLK, 0);
  if (qerr == hipSuccess && maxBlk >= 2) {
    int g = (maxBlk >= 3) ? 768 : 512;
    void* args[] = { &P };
    hipError_t lerr = hipLaunchCooperativeKernel((void*)k_all, dim3(g), dim3(BLK),
                                                 args, 0, stream);
    if (lerr == hipSuccess) return;
  }

  // ---- fallback: proven multi-kernel pipeline ----
  k_zero<<<(N_NODES + 512 + 255) / 256, 256, 0, stream>>>(P.cnt);
  k_hist<<<(N_EDGES + 255) / 256, 256, 0, stream>>>(P.ei, P.cnt);
  k_scan1<<<NB_SCAN, 256, 0, stream>>>(P.cnt, P.offs, P.bsum);
  k_scan2<<<1, 256, 0, stream>>>(P.bsum);
  k_scan3<<<NB_SCAN, 256, 0, stream>>>(P.offs, P.bsum, P.cursor);
  k_w6<<<1, 128, 0, stream>>>(P);
  k_scatter<<<(N_EDGES + 255) / 256, 256, 0, stream>>>(P);
  k_gather<<<(N_NODES + 255) / 256, 256, 0, stream>>>(P);
  k_fc<<<512, 128, 0, stream>>>(P);
  k_mfma<0><<<NTILES, 256, 0, stream>>>(P);
  k_mfma<1><<<NTILES, 256, 0, stream>>>(P);
}